// Round 9
// baseline (689.155 us; speedup 1.0000x reference)
//
#include <hip/hip_runtime.h>

typedef __attribute__((ext_vector_type(8))) short short8;
typedef __attribute__((ext_vector_type(4))) short short4_t;
typedef __attribute__((ext_vector_type(4))) float f32x4;

#define DEVI static __device__ __forceinline__

DEVI float b2f(short s) { return __uint_as_float(((unsigned)(unsigned short)s) << 16); }
DEVI short f2bs(float x) {
  unsigned u = __float_as_uint(x);
  unsigned r = (u + 0x7FFFu + ((u >> 16) & 1u)) >> 16;
  return (short)(unsigned short)r;
}

DEVI void gload16(const short* g, short* l) {
  __builtin_amdgcn_global_load_lds(
      (const __attribute__((address_space(1))) void*)g,
      (__attribute__((address_space(3))) void*)l, 16, 0, 0);
}

DEVI void wg_barrier() {
  asm volatile("" ::: "memory");
  __builtin_amdgcn_s_barrier();
  asm volatile("" ::: "memory");
}

// Stage one 128x64 bf16 unit: 8 waves x 2 gloads x 64 lanes x 16B = 16KB.
DEVI void stage_unit(const short* __restrict__ gTile, int K, int rowbase_w,
                     short* lUnit, int w, int l) {
  const int rr = l >> 3;
  const int slot = ((l & 7) ^ rr) << 3;
  const short* g0 = gTile + (size_t)(rowbase_w + rr) * K + slot;
  gload16(g0, lUnit + w * 1024);
  gload16(g0 + (size_t)8 * K, lUnit + w * 1024 + 512);
}

// ---- mask prefix scan: cpos[b][s] = #unmasked before s; count[b] = total ---
__global__ __launch_bounds__(256) void maskscan_kernel(const int* __restrict__ mask,
                                                       int* __restrict__ cpos,
                                                       int* __restrict__ count) {
  __shared__ int sums[257];
  const int b = blockIdx.x, t = threadIdx.x;
  const int* m = mask + b * 2048;
  int v[8], cs = 0;
#pragma unroll
  for (int i = 0; i < 8; i++) { v[i] = m[t * 8 + i] != 0 ? 1 : 0; cs += v[i]; }
  sums[t] = cs;
  __syncthreads();
  if (t == 0) {
    int acc = 0;
    for (int i = 0; i < 256; i++) { int x = sums[i]; sums[i] = acc; acc += x; }
    sums[256] = acc;
  }
  __syncthreads();
  int base = sums[t];
  int* cp = cpos + b * 2048 + t * 8;
#pragma unroll
  for (int i = 0; i < 8; i++) { cp[i] = base; base += v[i]; }
  if (t == 0) count[b] = sums[256];
}

// ---- prep: LN (text + compacted audio) AND weight transpose, one launch ---
__global__ __launch_bounds__(256) void prep_kernel(
    const float* __restrict__ text, const float* __restrict__ audio,
    const float* __restrict__ gt, const float* __restrict__ bt,
    const float* __restrict__ ga, const float* __restrict__ ba,
    const int* __restrict__ amask, const int* __restrict__ cpos,
    short* __restrict__ tb, short* __restrict__ ab,
    const float* __restrict__ Wq, const float* __restrict__ Wk,
    const float* __restrict__ Wv, short* __restrict__ Wqt,
    short* __restrict__ Wkt, short* __restrict__ Wvt) {
  const int bidx = blockIdx.x;
  if (bidx >= 24576) {
    // ---- weight transpose: W [K][N] fp32 -> Wt [N][K] bf16
    const int idx2 = bidx - 24576;          // 0..3071 = (32 x 32 x 3)
    const int z = idx2 >> 10;
    const float* W = z == 0 ? Wq : (z == 1 ? Wk : Wv);
    short* Wt = z == 0 ? Wqt : (z == 1 ? Wkt : Wvt);
    __shared__ float tile[32][33];
    const int tx = threadIdx.x & 31;
    const int ty = threadIdx.x >> 5;
    const int c0 = (idx2 & 31) * 32, r0 = ((idx2 >> 5) & 31) * 32;
#pragma unroll
    for (int rr = 0; rr < 4; rr++)
      tile[ty + rr * 8][tx] = W[(size_t)(r0 + ty + rr * 8) * 1024 + c0 + tx];
    __syncthreads();
#pragma unroll
    for (int rr = 0; rr < 4; rr++)
      Wt[(size_t)(c0 + ty + rr * 8) * 1024 + r0 + tx] = f2bs(tile[tx][ty + rr * 8]);
    return;
  }
  // ---- LayerNorm -> bf16 (audio rows compacted by mask)
  const size_t row = (size_t)bidx * 4 + (threadIdx.x >> 6);
  const int lane = threadIdx.x & 63;
  const float* X;
  const float* g;
  const float* b;
  short* Y;
  if (row < 32768) {
    X = text + row * 1024;
    g = gt; b = bt;
    Y = tb + row * 1024;
  } else {
    const size_t ar = row - 32768;
    if (amask[ar] == 0) return;
    const size_t bi = ar >> 11;
    X = audio + ar * 1024;
    g = ga; b = ba;
    Y = ab + (bi * 2048 + (size_t)cpos[ar]) * 1024;
  }
  f32x4 x[4];
  float s = 0.f, ss = 0.f;
#pragma unroll
  for (int j = 0; j < 4; j++) {
    x[j] = *(const f32x4*)(X + j * 256 + lane * 4);
#pragma unroll
    for (int c = 0; c < 4; c++) { s += x[j][c]; ss += x[j][c] * x[j][c]; }
  }
  for (int o = 32; o > 0; o >>= 1) { s += __shfl_xor(s, o, 64); ss += __shfl_xor(ss, o, 64); }
  const float m = s * (1.f / 1024.f);
  const float rstd = rsqrtf(ss * (1.f / 1024.f) - m * m + 1e-5f);
#pragma unroll
  for (int j = 0; j < 4; j++) {
    f32x4 gg = *(const f32x4*)(g + j * 256 + lane * 4);
    f32x4 bb = *(const f32x4*)(b + j * 256 + lane * 4);
    short4_t o4;
#pragma unroll
    for (int c = 0; c < 4; c++) o4[c] = f2bs((x[j][c] - m) * rstd * gg[c] + bb[c]);
    *(short4_t*)(Y + j * 256 + lane * 4) = o4;
  }
}

// ============ 256x256 4-phase MFMA GEMM core (r6-proven) ====================
// EXIT 0: none | 1: return if rowBase >= cnt[bz] | 2: return if colBase >= cnt[bz]
// EPI 0: +bias[col] bf16 | 1: exp(s*scale) for col<cnt + row partials
// EPI 3: +bias[row] bf16 | 5: *rsinv[row] bf16, dynamic K-trip from cnt
template <int EPI, int EXIT>
DEVI void gemm_core(
    const short* __restrict__ A, const short* __restrict__ B, void* __restrict__ Cp,
    int K, int ldc, long Abatch, long Bbatch, long Cbatch,
    const float* __restrict__ bias, float scale,
    float* __restrict__ partial, const float* __restrict__ rsinv,
    const int* __restrict__ cnt, int bx, int by, int bz, short* lds) {
  const int t = threadIdx.x;
  const int w = t >> 6, l = t & 63;
  const int wm = w >> 2, wn = w & 3;
  const int fr = l & 15, fg = l >> 4, fr7 = l & 7;

  const int rowBase = by * 256;
  const int colBase = bx * 256;

  int cntv = 0x7fffffff;
  if (EXIT != 0 || EPI == 5) cntv = cnt[bz];

  if (EXIT == 1 && rowBase >= cntv) return;
  if (EXIT == 2 && colBase >= cntv) {
    if (EPI == 1) {
#pragma unroll
      for (int mi = 0; mi < 8; mi++)
#pragma unroll
        for (int j = 0; j < 4; j++) {
          const int rowl = rowBase + wm * 128 + mi * 16 + fg * 4 + j;
          if ((l & 15) == 0)
            partial[((size_t)bz * 1024 + rowl) * 32 + bx * 4 + wn] = 0.f;
        }
    }
    return;
  }

  const short* Ab = A + (size_t)bz * Abatch + (size_t)rowBase * K;
  const short* Bb = B + (size_t)bz * Bbatch + (size_t)colBase * K;

  short* As = lds;            // [buf][reg][128][64]
  short* Bs = lds + 32768;

  f32x4 acc[8][4];
#pragma unroll
  for (int m = 0; m < 8; m++)
#pragma unroll
    for (int n = 0; n < 4; n++) acc[m][n] = (f32x4){0.f, 0.f, 0.f, 0.f};

  int nt = K >> 6;
  if (EPI == 5) {
    int ntb = (cntv + 63) >> 6;
    nt = ntb < nt ? ntb : nt;
    if (nt < 1) nt = 1;
  }
  const int ntm1 = nt - 1;

  const int rbA0 = (w >> 2) * 128 + (w & 3) * 16;
  const int rbA1 = rbA0 + 64;
  const int rbB0 = (w >> 1) * 64 + (w & 1) * 16;
  const int rbB1 = rbB0 + 32;

  // ---- prologue: 7 units (tile0 all 4, tile1 first 3)
  stage_unit(Ab, K, rbA0, As, w, l);
  stage_unit(Bb, K, rbB0, Bs, w, l);
  stage_unit(Ab, K, rbA1, As + 8192, w, l);
  stage_unit(Bb, K, rbB1, Bs + 8192, w, l);
  {
    const int kp = (nt > 1) ? 64 : 0;
    stage_unit(Ab + kp, K, rbA0, As + 16384, w, l);
    stage_unit(Bb + kp, K, rbB0, Bs + 16384, w, l);
    stage_unit(Ab + kp, K, rbA1, As + 24576, w, l);
  }
  asm volatile("s_waitcnt vmcnt(6)" ::: "memory");
  wg_barrier();

  const int rowA = (wm * 64 + fr) * 64;
  const int rowB = (wn * 32 + fr) * 64;
  const int ks0 = (fg ^ fr7) << 3;
  const int ks1 = ((4 + fg) ^ fr7) << 3;

  short8 aL[4][2], aH[4][2], bF[2][2];

  for (int tt = 0; tt < nt; ++tt) {
    const int c = tt & 1;
    const short* Ac = As + c * 16384;
    const short* Bc = Bs + c * 16384;
    short* Acur = As + c * 16384;
    short* Bcur = Bs + c * 16384;
    short* Bnx = Bs + (c ^ 1) * 16384;
    const int k1 = ((tt + 1 <= ntm1) ? tt + 1 : ntm1) * 64;
    const int k2 = ((tt + 2 <= ntm1) ? tt + 2 : ntm1) * 64;

    // ---- P0: quadrant (mh0,nh0); 12 ds_reads; stage B-r1(t+1)
#pragma unroll
    for (int m = 0; m < 4; m++) {
      aL[m][0] = *(const short8*)&Ac[rowA + m * 1024 + ks0];
      aL[m][1] = *(const short8*)&Ac[rowA + m * 1024 + ks1];
    }
#pragma unroll
    for (int n = 0; n < 2; n++) {
      bF[n][0] = *(const short8*)&Bc[rowB + n * 1024 + ks0];
      bF[n][1] = *(const short8*)&Bc[rowB + n * 1024 + ks1];
    }
    stage_unit(Bb + k1, K, rbB1, Bnx + 8192, w, l);
    wg_barrier();
    __builtin_amdgcn_s_setprio(1);
#pragma unroll
    for (int m = 0; m < 4; m++)
#pragma unroll
      for (int n = 0; n < 2; n++) {
        acc[m][n] = __builtin_amdgcn_mfma_f32_16x16x32_bf16(aL[m][0], bF[n][0], acc[m][n], 0, 0, 0);
        acc[m][n] = __builtin_amdgcn_mfma_f32_16x16x32_bf16(aL[m][1], bF[n][1], acc[m][n], 0, 0, 0);
      }
    __builtin_amdgcn_s_setprio(0);
    wg_barrier();

    // ---- P1: quadrant (mh1,nh0); 8 ds_reads; stage A-r0(t+2)
#pragma unroll
    for (int m = 0; m < 4; m++) {
      aH[m][0] = *(const short8*)&Ac[8192 + rowA + m * 1024 + ks0];
      aH[m][1] = *(const short8*)&Ac[8192 + rowA + m * 1024 + ks1];
    }
    stage_unit(Ab + k2, K, rbA0, Acur, w, l);
    wg_barrier();
    __builtin_amdgcn_s_setprio(1);
#pragma unroll
    for (int m = 0; m < 4; m++)
#pragma unroll
      for (int n = 0; n < 2; n++) {
        acc[4 + m][n] = __builtin_amdgcn_mfma_f32_16x16x32_bf16(aH[m][0], bF[n][0], acc[4 + m][n], 0, 0, 0);
        acc[4 + m][n] = __builtin_amdgcn_mfma_f32_16x16x32_bf16(aH[m][1], bF[n][1], acc[4 + m][n], 0, 0, 0);
      }
    __builtin_amdgcn_s_setprio(0);
    wg_barrier();

    // ---- P2: quadrant (mh0,nh1); 4 ds_reads; stage B-r0(t+2)
#pragma unroll
    for (int n = 0; n < 2; n++) {
      bF[n][0] = *(const short8*)&Bc[8192 + rowB + n * 1024 + ks0];
      bF[n][1] = *(const short8*)&Bc[8192 + rowB + n * 1024 + ks1];
    }
    stage_unit(Bb + k2, K, rbB0, Bcur, w, l);
    wg_barrier();
    __builtin_amdgcn_s_setprio(1);
#pragma unroll
    for (int m = 0; m < 4; m++)
#pragma unroll
      for (int n = 0; n < 2; n++) {
        acc[m][2 + n] = __builtin_amdgcn_mfma_f32_16x16x32_bf16(aL[m][0], bF[n][0], acc[m][2 + n], 0, 0, 0);
        acc[m][2 + n] = __builtin_amdgcn_mfma_f32_16x16x32_bf16(aL[m][1], bF[n][1], acc[m][2 + n], 0, 0, 0);
      }
    __builtin_amdgcn_s_setprio(0);
    wg_barrier();

    // ---- P3: quadrant (mh1,nh1); 0 ds_reads; stage A-r1(t+2)
    stage_unit(Ab + k2, K, rbA1, Acur + 8192, w, l);
    wg_barrier();
    __builtin_amdgcn_s_setprio(1);
#pragma unroll
    for (int m = 0; m < 4; m++)
#pragma unroll
      for (int n = 0; n < 2; n++) {
        acc[4 + m][2 + n] = __builtin_amdgcn_mfma_f32_16x16x32_bf16(aH[m][0], bF[n][0], acc[4 + m][2 + n], 0, 0, 0);
        acc[4 + m][2 + n] = __builtin_amdgcn_mfma_f32_16x16x32_bf16(aH[m][1], bF[n][1], acc[4 + m][2 + n], 0, 0, 0);
      }
    __builtin_amdgcn_s_setprio(0);
    asm volatile("s_waitcnt vmcnt(6)" ::: "memory");
    wg_barrier();
  }

  // ---- epilogue
  if (EPI == 0) {
    short* C = (short*)Cp + (size_t)bz * Cbatch;
#pragma unroll
    for (int ni = 0; ni < 4; ni++) {
      const int col = colBase + wn * 64 + ni * 16 + fr;
      const float bb = bias[col];
#pragma unroll
      for (int mi = 0; mi < 8; mi++)
#pragma unroll
        for (int j = 0; j < 4; j++) {
          const size_t row = (size_t)rowBase + wm * 128 + mi * 16 + fg * 4 + j;
          C[row * (size_t)ldc + col] = f2bs(acc[mi][ni][j] + bb);
        }
    }
  } else if (EPI == 1) {
    short* C = (short*)Cp + (size_t)bz * Cbatch;
    bool mk[4];
    int cols[4];
#pragma unroll
    for (int ni = 0; ni < 4; ni++) {
      cols[ni] = colBase + wn * 64 + ni * 16 + fr;
      mk[ni] = cols[ni] < cntv;
    }
#pragma unroll
    for (int mi = 0; mi < 8; mi++)
#pragma unroll
      for (int j = 0; j < 4; j++) {
        const int rowl = rowBase + wm * 128 + mi * 16 + fg * 4 + j;
        float s = 0.f;
#pragma unroll
        for (int ni = 0; ni < 4; ni++) {
          const float e = mk[ni] ? __expf(fminf(acc[mi][ni][j] * scale, 30.f)) : 0.f;
          const short eb = f2bs(e);
          C[(size_t)rowl * (size_t)ldc + cols[ni]] = eb;
          s += b2f(eb);
        }
        s += __shfl_xor(s, 1, 64);
        s += __shfl_xor(s, 2, 64);
        s += __shfl_xor(s, 4, 64);
        s += __shfl_xor(s, 8, 64);
        if ((l & 15) == 0)
          partial[((size_t)bz * 1024 + rowl) * 32 + bx * 4 + wn] = s;
      }
  } else if (EPI == 3) {
    short* C = (short*)Cp + (size_t)bz * Cbatch;
#pragma unroll
    for (int mi = 0; mi < 8; mi++) {
      f32x4 b4 = *(const f32x4*)&bias[rowBase + wm * 128 + mi * 16 + fg * 4];
#pragma unroll
      for (int ni = 0; ni < 4; ni++) {
        const int col = colBase + wn * 64 + ni * 16 + fr;
#pragma unroll
        for (int j = 0; j < 4; j++) {
          const size_t row = (size_t)rowBase + wm * 128 + mi * 16 + fg * 4 + j;
          C[row * (size_t)ldc + col] = f2bs(acc[mi][ni][j] + b4[j]);
        }
      }
    }
  } else {
    // EPI 5: PV, multiply by rsinv[row], bf16 out
    short* C = (short*)Cp + (size_t)bz * Cbatch;
#pragma unroll
    for (int mi = 0; mi < 8; mi++) {
      const int rbase = rowBase + wm * 128 + mi * 16 + fg * 4;
      f32x4 rv = *(const f32x4*)&rsinv[(size_t)bz * 1024 + rbase];
#pragma unroll
      for (int ni = 0; ni < 4; ni++) {
        const int col = colBase + wn * 64 + ni * 16 + fr;
#pragma unroll
        for (int j = 0; j < 4; j++)
          C[((size_t)rbase + j) * (size_t)ldc + col] = f2bs(acc[mi][ni][j] * rv[j]);
      }
    }
  }
}

// ---- merged QKV: 2560 linear blocks = q(512) + k(1024) + vT(1024) ---------
__global__ __launch_bounds__(512, 2) void qkv_kernel(
    const short* __restrict__ tb, const short* __restrict__ Wqt,
    short* __restrict__ qb, const float* __restrict__ bq,
    const short* __restrict__ ab, const short* __restrict__ Wkt,
    short* __restrict__ kb, const float* __restrict__ bk,
    const short* __restrict__ Wvt, short* __restrict__ vTb,
    const float* __restrict__ bv, const int* __restrict__ cnt) {
  __shared__ short lds[65536];
  const int nwg = gridDim.x;  // 2560, %8 == 0
  const int o = blockIdx.x;
  const int lin = (o & 7) * (nwg >> 3) + (o >> 3);
  if (lin < 512) {
    // q = tb @ Wqt^T + bq : gx=4, gy=128
    gemm_core<0, 0>(tb, Wqt, qb, 1024, 1024, 0, 0, 0, bq, 0.f,
                    nullptr, nullptr, nullptr, lin & 3, lin >> 2, 0, lds);
  } else if (lin < 1536) {
    // kc = ab_c @ Wkt^T + bk per batch: gx=4, gy=8, gz=32, EXIT on rows
    const int r = lin - 512;
    gemm_core<0, 1>(ab, Wkt, kb, 1024, 1024, (long)2048 * 1024, 0,
                    (long)2048 * 1024, bk, 0.f, nullptr, nullptr, cnt,
                    r & 3, (r >> 2) & 7, r >> 5, lds);
  } else {
    // vTc = (ab_c @ Wvt^T + bv)^T: gx=8, gy=4, gz=32, EXIT on cols
    const int r = lin - 1536;
    gemm_core<3, 2>(Wvt, ab, vTb, 1024, 2048, 0, (long)2048 * 1024,
                    (long)1024 * 2048, bv, 0.f, nullptr, nullptr, cnt,
                    r & 7, (r >> 3) & 3, r >> 5, lds);
  }
}

// ---- standalone GEMM (scores / PV), 3D grid with XCD swizzle --------------
template <int EPI, int EXIT>
__global__ __launch_bounds__(512, 2) void gemm8_kernel(
    const short* __restrict__ A, const short* __restrict__ B, void* __restrict__ Cp,
    int K, int ldc, long Abatch, long Bbatch, long Cbatch,
    const float* __restrict__ bias, float scale,
    float* __restrict__ partial, const float* __restrict__ rsinv,
    const int* __restrict__ cnt) {
  __shared__ short lds[65536];
  const int gx = gridDim.x, gy = gridDim.y;
  const int nwg = gx * gy * (int)gridDim.z;
  int lin = blockIdx.x + gx * (blockIdx.y + gy * blockIdx.z);
  lin = (lin & 7) * (nwg >> 3) + (lin >> 3);
  const int bx = lin % gx;
  const int by = (lin / gx) % gy;
  const int bz = lin / (gx * gy);
  gemm_core<EPI, EXIT>(A, B, Cp, K, ldc, Abatch, Bbatch, Cbatch, bias, scale,
                       partial, rsinv, cnt, bx, by, bz, lds);
}

// ---------------- row-sum reduce: rsinv = 1 / sum(partial[row][0..32)) -----
__global__ __launch_bounds__(256) void rsum_kernel(const float* __restrict__ partial,
                                                   float* __restrict__ rsinv) {
  const size_t r = (size_t)blockIdx.x * 256 + threadIdx.x;
  float s = 0.f;
#pragma unroll
  for (int j = 0; j < 8; j++) {
    f32x4 a = *(const f32x4*)(partial + r * 32 + j * 4);
    s += (a[0] + a[1]) + (a[2] + a[3]);
  }
  rsinv[r] = 1.f / fmaxf(s, 1e-30f);
}

// -------- final LayerNorm: bf16 in (cross), fp32 out (d_out) ---------------
__global__ __launch_bounds__(256) void final_ln_kernel(const short* __restrict__ X,
                                                       const float* __restrict__ g,
                                                       const float* __restrict__ b,
                                                       float* __restrict__ Y) {
  const size_t row = (size_t)blockIdx.x * 4 + (threadIdx.x >> 6);
  const int lane = threadIdx.x & 63;
  const short* r = X + row * 1024;
  float f[16];
  float s = 0.f, ss = 0.f;
#pragma unroll
  for (int j = 0; j < 2; j++) {
    short8 v = *(const short8*)(r + j * 512 + lane * 8);
#pragma unroll
    for (int i = 0; i < 8; i++) {
      float x = b2f(v[i]);
      f[j * 8 + i] = x;
      s += x;
      ss += x * x;
    }
  }
  for (int o = 32; o > 0; o >>= 1) { s += __shfl_xor(s, o, 64); ss += __shfl_xor(ss, o, 64); }
  const float m = s * (1.f / 1024.f);
  const float rstd = rsqrtf(ss * (1.f / 1024.f) - m * m + 1e-5f);
#pragma unroll
  for (int j = 0; j < 2; j++) {
#pragma unroll
    for (int q = 0; q < 2; q++) {
      const int off = j * 512 + lane * 8 + q * 4;
      f32x4 gg = *(const f32x4*)(g + off);
      f32x4 bb = *(const f32x4*)(b + off);
      f32x4 y;
#pragma unroll
      for (int c = 0; c < 4; c++) y[c] = (f[j * 8 + q * 4 + c] - m) * rstd * gg[c] + bb[c];
      *(f32x4*)(Y + row * 1024 + off) = y;
    }
  }
}

extern "C" void kernel_launch(void* const* d_in, const int* in_sizes, int n_in,
                              void* d_out, int out_size, void* d_ws, size_t ws_size,
                              hipStream_t stream) {
  const float* text = (const float*)d_in[0];
  const float* audio = (const float*)d_in[1];
  const int* amask = (const int*)d_in[2];
  const float* ln_t_g = (const float*)d_in[3];
  const float* ln_t_b = (const float*)d_in[4];
  const float* ln_a_g = (const float*)d_in[5];
  const float* ln_a_b = (const float*)d_in[6];
  const float* Wq = (const float*)d_in[7];
  const float* bq = (const float*)d_in[8];
  const float* Wk = (const float*)d_in[9];
  const float* bk = (const float*)d_in[10];
  const float* Wv = (const float*)d_in[11];
  const float* bv = (const float*)d_in[12];
  const float* ln_p_g = (const float*)d_in[13];
  const float* ln_p_b = (const float*)d_in[14];

  char* p = (char*)d_ws;
  short* tb = (short*)p;  p += (size_t)32768 * 1024 * 2;      // 64 MB  (LN text)
  short* ab = (short*)p;  p += (size_t)65536 * 1024 * 2;      // 128 MB (LN audio, compacted)
  short* Wqt = (short*)p; p += (size_t)1024 * 1024 * 2;
  short* Wkt = (short*)p; p += (size_t)1024 * 1024 * 2;
  short* Wvt = (short*)p; p += (size_t)1024 * 1024 * 2;
  short* qb = (short*)p;  p += (size_t)32768 * 1024 * 2;      // 64 MB
  short* kb = (short*)p;  p += (size_t)65536 * 1024 * 2;      // 128 MB (compacted rows)
  short* vTb = (short*)p; p += (size_t)32 * 1024 * 2048 * 2;  // 128 MB [b][d][s-compact]
  float* partial = (float*)p; p += (size_t)32768 * 32 * 4;    // 4 MB
  float* rsinv = (float*)p;   p += (size_t)32768 * 4;         // 128 KB
  int* cpos = (int*)p;        p += (size_t)32 * 2048 * 4;     // 256 KB
  int* cnt = (int*)p;         p += 256;
  short* Pb = tb;       // P aliases tb+ab
  short* crossb = qb;   // cross aliases qb
  (void)ws_size; (void)in_sizes; (void)n_in; (void)out_size;

  // 0. mask prefix scan
  maskscan_kernel<<<32, 256, 0, stream>>>(amask, cpos, cnt);
  // 1. prep: LN (text + compacted audio) + weight transpose, one launch
  prep_kernel<<<24576 + 3072, 256, 0, stream>>>(
      text, audio, ln_t_g, ln_t_b, ln_a_g, ln_a_b, amask, cpos, tb, ab,
      Wq, Wk, Wv, Wqt, Wkt, Wvt);
  // 2. merged q/k/vT projections (packed grid)
  qkv_kernel<<<2560, 512, 0, stream>>>(tb, Wqt, qb, bq, ab, Wkt, kb, bk,
                                       Wvt, vTb, bv, cnt);
  // 3. P = exp(scale * q@kc^T) for col<cnt -> bf16 + row partials, early-exit
  gemm8_kernel<1, 2><<<dim3(8, 4, 32), 512, 0, stream>>>(
      qb, kb, Pb, 1024, 2048, (long)1024 * 1024, (long)2048 * 1024,
      (long)1024 * 2048, nullptr, 0.03125f, partial, nullptr, cnt);
  // 4. rsinv[row] = 1 / sum_j partial[row][j]
  rsum_kernel<<<128, 256, 0, stream>>>(partial, rsinv);
  // 5. cross = (P @ vTc^T) * rsinv -> bf16, dynamic K-trip = ceil(cnt/64)
  gemm8_kernel<5, 0><<<dim3(4, 4, 32), 512, 0, stream>>>(
      Pb, vTb, crossb, 2048, 1024, (long)1024 * 2048, (long)1024 * 2048,
      (long)1024 * 1024, nullptr, 0.f, nullptr, rsinv, cnt);
  // 6. final LayerNorm: crossb (bf16) -> d_out (fp32)
  final_ln_kernel<<<8192, 256, 0, stream>>>(crossb, ln_p_g, ln_p_b, (float*)d_out);
}

// Round 10
// 624.737 us; speedup vs baseline: 1.1031x; 1.1031x over previous
//
#include <hip/hip_runtime.h>

typedef __attribute__((ext_vector_type(8))) short short8;
typedef __attribute__((ext_vector_type(4))) short short4_t;
typedef __attribute__((ext_vector_type(4))) float f32x4;

#define DEVI static __device__ __forceinline__

DEVI float b2f(short s) { return __uint_as_float(((unsigned)(unsigned short)s) << 16); }
DEVI short f2bs(float x) {
  unsigned u = __float_as_uint(x);
  unsigned r = (u + 0x7FFFu + ((u >> 16) & 1u)) >> 16;
  return (short)(unsigned short)r;
}

DEVI void gload16(const short* g, short* l) {
  __builtin_amdgcn_global_load_lds(
      (const __attribute__((address_space(1))) void*)g,
      (__attribute__((address_space(3))) void*)l, 16, 0, 0);
}

DEVI void wg_barrier() {
  asm volatile("" ::: "memory");
  __builtin_amdgcn_s_barrier();
  asm volatile("" ::: "memory");
}

// Stage one 128x64 bf16 unit: 8 waves x 2 gloads x 64 lanes x 16B = 16KB.
DEVI void stage_unit(const short* __restrict__ gTile, int K, int rowbase_w,
                     short* lUnit, int w, int l) {
  const int rr = l >> 3;
  const int slot = ((l & 7) ^ rr) << 3;
  const short* g0 = gTile + (size_t)(rowbase_w + rr) * K + slot;
  gload16(g0, lUnit + w * 1024);
  gload16(g0 + (size_t)8 * K, lUnit + w * 1024 + 512);
}

// ---- mask prefix scan: cpos[b][s] = #unmasked before s; count[b] = total ---
__global__ __launch_bounds__(256) void maskscan_kernel(const int* __restrict__ mask,
                                                       int* __restrict__ cpos,
                                                       int* __restrict__ count) {
  __shared__ int sums[257];
  const int b = blockIdx.x, t = threadIdx.x;
  const int* m = mask + b * 2048;
  int v[8], cs = 0;
#pragma unroll
  for (int i = 0; i < 8; i++) { v[i] = m[t * 8 + i] != 0 ? 1 : 0; cs += v[i]; }
  sums[t] = cs;
  __syncthreads();
  if (t == 0) {
    int acc = 0;
    for (int i = 0; i < 256; i++) { int x = sums[i]; sums[i] = acc; acc += x; }
    sums[256] = acc;
  }
  __syncthreads();
  int base = sums[t];
  int* cp = cpos + b * 2048 + t * 8;
#pragma unroll
  for (int i = 0; i < 8; i++) { cp[i] = base; base += v[i]; }
  if (t == 0) count[b] = sums[256];
}

// ---- prep: LN (text + compacted audio) AND weight transpose, one launch ---
__global__ __launch_bounds__(256) void prep_kernel(
    const float* __restrict__ text, const float* __restrict__ audio,
    const float* __restrict__ gt, const float* __restrict__ bt,
    const float* __restrict__ ga, const float* __restrict__ ba,
    const int* __restrict__ amask, const int* __restrict__ cpos,
    short* __restrict__ tb, short* __restrict__ ab,
    const float* __restrict__ Wq, const float* __restrict__ Wk,
    const float* __restrict__ Wv, short* __restrict__ Wqt,
    short* __restrict__ Wkt, short* __restrict__ Wvt) {
  const int bidx = blockIdx.x;
  if (bidx >= 24576) {
    // ---- weight transpose: W [K][N] fp32 -> Wt [N][K] bf16
    const int idx2 = bidx - 24576;          // 0..3071 = (32 x 32 x 3)
    const int z = idx2 >> 10;
    const float* W = z == 0 ? Wq : (z == 1 ? Wk : Wv);
    short* Wt = z == 0 ? Wqt : (z == 1 ? Wkt : Wvt);
    __shared__ float tile[32][33];
    const int tx = threadIdx.x & 31;
    const int ty = threadIdx.x >> 5;
    const int c0 = (idx2 & 31) * 32, r0 = ((idx2 >> 5) & 31) * 32;
#pragma unroll
    for (int rr = 0; rr < 4; rr++)
      tile[ty + rr * 8][tx] = W[(size_t)(r0 + ty + rr * 8) * 1024 + c0 + tx];
    __syncthreads();
#pragma unroll
    for (int rr = 0; rr < 4; rr++)
      Wt[(size_t)(c0 + ty + rr * 8) * 1024 + r0 + tx] = f2bs(tile[tx][ty + rr * 8]);
    return;
  }
  // ---- LayerNorm -> bf16 (audio rows compacted by mask)
  const size_t row = (size_t)bidx * 4 + (threadIdx.x >> 6);
  const int lane = threadIdx.x & 63;
  const float* X;
  const float* g;
  const float* b;
  short* Y;
  if (row < 32768) {
    X = text + row * 1024;
    g = gt; b = bt;
    Y = tb + row * 1024;
  } else {
    const size_t ar = row - 32768;
    if (amask[ar] == 0) return;
    const size_t bi = ar >> 11;
    X = audio + ar * 1024;
    g = ga; b = ba;
    Y = ab + (bi * 2048 + (size_t)cpos[ar]) * 1024;
  }
  f32x4 x[4];
  float s = 0.f, ss = 0.f;
#pragma unroll
  for (int j = 0; j < 4; j++) {
    x[j] = *(const f32x4*)(X + j * 256 + lane * 4);
#pragma unroll
    for (int c = 0; c < 4; c++) { s += x[j][c]; ss += x[j][c] * x[j][c]; }
  }
  for (int o = 32; o > 0; o >>= 1) { s += __shfl_xor(s, o, 64); ss += __shfl_xor(ss, o, 64); }
  const float m = s * (1.f / 1024.f);
  const float rstd = rsqrtf(ss * (1.f / 1024.f) - m * m + 1e-5f);
#pragma unroll
  for (int j = 0; j < 4; j++) {
    f32x4 gg = *(const f32x4*)(g + j * 256 + lane * 4);
    f32x4 bb = *(const f32x4*)(b + j * 256 + lane * 4);
    short4_t o4;
#pragma unroll
    for (int c = 0; c < 4; c++) o4[c] = f2bs((x[j][c] - m) * rstd * gg[c] + bb[c]);
    *(short4_t*)(Y + j * 256 + lane * 4) = o4;
  }
}

// ============ 256x256 4-phase MFMA GEMM core (r6-proven) ====================
// EXIT 0: none | 1: return if rowBase >= cnt[bz] | 2: return if colBase >= cnt[bz]
// EPI 0: +bias[col] bf16 | 1: exp(s*scale) for col<cnt + row partials
// EPI 3: +bias[row] bf16 | 5: *rsinv[row] bf16, dynamic K-trip from cnt
template <int EPI, int EXIT>
DEVI void gemm_core(
    const short* __restrict__ A, const short* __restrict__ B, void* __restrict__ Cp,
    int K, int ldc, long Abatch, long Bbatch, long Cbatch,
    const float* __restrict__ bias, float scale,
    float* __restrict__ partial, const float* __restrict__ rsinv,
    const int* __restrict__ cnt, int bx, int by, int bz, short* lds) {
  const int t = threadIdx.x;
  const int w = t >> 6, l = t & 63;
  const int wm = w >> 2, wn = w & 3;
  const int fr = l & 15, fg = l >> 4, fr7 = l & 7;

  const int rowBase = by * 256;
  const int colBase = bx * 256;

  int cntv = 0x7fffffff;
  if (EXIT != 0 || EPI == 5) cntv = cnt[bz];

  if (EXIT == 1 && rowBase >= cntv) return;
  if (EXIT == 2 && colBase >= cntv) {
    if (EPI == 1) {
#pragma unroll
      for (int mi = 0; mi < 8; mi++)
#pragma unroll
        for (int j = 0; j < 4; j++) {
          const int rowl = rowBase + wm * 128 + mi * 16 + fg * 4 + j;
          if ((l & 15) == 0)
            partial[((size_t)bz * 1024 + rowl) * 32 + bx * 4 + wn] = 0.f;
        }
    }
    return;
  }

  const short* Ab = A + (size_t)bz * Abatch + (size_t)rowBase * K;
  const short* Bb = B + (size_t)bz * Bbatch + (size_t)colBase * K;

  short* As = lds;            // [buf][reg][128][64]
  short* Bs = lds + 32768;

  f32x4 acc[8][4];
#pragma unroll
  for (int m = 0; m < 8; m++)
#pragma unroll
    for (int n = 0; n < 4; n++) acc[m][n] = (f32x4){0.f, 0.f, 0.f, 0.f};

  int nt = K >> 6;
  if (EPI == 5) {
    int ntb = (cntv + 63) >> 6;
    nt = ntb < nt ? ntb : nt;
    if (nt < 1) nt = 1;
  }
  const int ntm1 = nt - 1;

  const int rbA0 = (w >> 2) * 128 + (w & 3) * 16;
  const int rbA1 = rbA0 + 64;
  const int rbB0 = (w >> 1) * 64 + (w & 1) * 16;
  const int rbB1 = rbB0 + 32;

  // ---- prologue: 7 units (tile0 all 4, tile1 first 3)
  stage_unit(Ab, K, rbA0, As, w, l);
  stage_unit(Bb, K, rbB0, Bs, w, l);
  stage_unit(Ab, K, rbA1, As + 8192, w, l);
  stage_unit(Bb, K, rbB1, Bs + 8192, w, l);
  {
    const int kp = (nt > 1) ? 64 : 0;
    stage_unit(Ab + kp, K, rbA0, As + 16384, w, l);
    stage_unit(Bb + kp, K, rbB0, Bs + 16384, w, l);
    stage_unit(Ab + kp, K, rbA1, As + 24576, w, l);
  }
  asm volatile("s_waitcnt vmcnt(6)" ::: "memory");
  wg_barrier();

  const int rowA = (wm * 64 + fr) * 64;
  const int rowB = (wn * 32 + fr) * 64;
  const int ks0 = (fg ^ fr7) << 3;
  const int ks1 = ((4 + fg) ^ fr7) << 3;

  short8 aL[4][2], aH[4][2], bF[2][2];

  for (int tt = 0; tt < nt; ++tt) {
    const int c = tt & 1;
    const short* Ac = As + c * 16384;
    const short* Bc = Bs + c * 16384;
    short* Acur = As + c * 16384;
    short* Bcur = Bs + c * 16384;
    short* Bnx = Bs + (c ^ 1) * 16384;
    const int k1 = ((tt + 1 <= ntm1) ? tt + 1 : ntm1) * 64;
    const int k2 = ((tt + 2 <= ntm1) ? tt + 2 : ntm1) * 64;

    // ---- P0: quadrant (mh0,nh0); 12 ds_reads; stage B-r1(t+1)
#pragma unroll
    for (int m = 0; m < 4; m++) {
      aL[m][0] = *(const short8*)&Ac[rowA + m * 1024 + ks0];
      aL[m][1] = *(const short8*)&Ac[rowA + m * 1024 + ks1];
    }
#pragma unroll
    for (int n = 0; n < 2; n++) {
      bF[n][0] = *(const short8*)&Bc[rowB + n * 1024 + ks0];
      bF[n][1] = *(const short8*)&Bc[rowB + n * 1024 + ks1];
    }
    stage_unit(Bb + k1, K, rbB1, Bnx + 8192, w, l);
    wg_barrier();
    __builtin_amdgcn_s_setprio(1);
#pragma unroll
    for (int m = 0; m < 4; m++)
#pragma unroll
      for (int n = 0; n < 2; n++) {
        acc[m][n] = __builtin_amdgcn_mfma_f32_16x16x32_bf16(aL[m][0], bF[n][0], acc[m][n], 0, 0, 0);
        acc[m][n] = __builtin_amdgcn_mfma_f32_16x16x32_bf16(aL[m][1], bF[n][1], acc[m][n], 0, 0, 0);
      }
    __builtin_amdgcn_s_setprio(0);
    wg_barrier();

    // ---- P1: quadrant (mh1,nh0); 8 ds_reads; stage A-r0(t+2)
#pragma unroll
    for (int m = 0; m < 4; m++) {
      aH[m][0] = *(const short8*)&Ac[8192 + rowA + m * 1024 + ks0];
      aH[m][1] = *(const short8*)&Ac[8192 + rowA + m * 1024 + ks1];
    }
    stage_unit(Ab + k2, K, rbA0, Acur, w, l);
    wg_barrier();
    __builtin_amdgcn_s_setprio(1);
#pragma unroll
    for (int m = 0; m < 4; m++)
#pragma unroll
      for (int n = 0; n < 2; n++) {
        acc[4 + m][n] = __builtin_amdgcn_mfma_f32_16x16x32_bf16(aH[m][0], bF[n][0], acc[4 + m][n], 0, 0, 0);
        acc[4 + m][n] = __builtin_amdgcn_mfma_f32_16x16x32_bf16(aH[m][1], bF[n][1], acc[4 + m][n], 0, 0, 0);
      }
    __builtin_amdgcn_s_setprio(0);
    wg_barrier();

    // ---- P2: quadrant (mh0,nh1); 4 ds_reads; stage B-r0(t+2)
#pragma unroll
    for (int n = 0; n < 2; n++) {
      bF[n][0] = *(const short8*)&Bc[8192 + rowB + n * 1024 + ks0];
      bF[n][1] = *(const short8*)&Bc[8192 + rowB + n * 1024 + ks1];
    }
    stage_unit(Bb + k2, K, rbB0, Bcur, w, l);
    wg_barrier();
    __builtin_amdgcn_s_setprio(1);
#pragma unroll
    for (int m = 0; m < 4; m++)
#pragma unroll
      for (int n = 0; n < 2; n++) {
        acc[m][2 + n] = __builtin_amdgcn_mfma_f32_16x16x32_bf16(aL[m][0], bF[n][0], acc[m][2 + n], 0, 0, 0);
        acc[m][2 + n] = __builtin_amdgcn_mfma_f32_16x16x32_bf16(aL[m][1], bF[n][1], acc[m][2 + n], 0, 0, 0);
      }
    __builtin_amdgcn_s_setprio(0);
    wg_barrier();

    // ---- P3: quadrant (mh1,nh1); 0 ds_reads; stage A-r1(t+2)
    stage_unit(Ab + k2, K, rbA1, Acur + 8192, w, l);
    wg_barrier();
    __builtin_amdgcn_s_setprio(1);
#pragma unroll
    for (int m = 0; m < 4; m++)
#pragma unroll
      for (int n = 0; n < 2; n++) {
        acc[4 + m][2 + n] = __builtin_amdgcn_mfma_f32_16x16x32_bf16(aH[m][0], bF[n][0], acc[4 + m][2 + n], 0, 0, 0);
        acc[4 + m][2 + n] = __builtin_amdgcn_mfma_f32_16x16x32_bf16(aH[m][1], bF[n][1], acc[4 + m][2 + n], 0, 0, 0);
      }
    __builtin_amdgcn_s_setprio(0);
    asm volatile("s_waitcnt vmcnt(6)" ::: "memory");
    wg_barrier();
  }

  // ---- epilogue
  if (EPI == 0) {
    short* C = (short*)Cp + (size_t)bz * Cbatch;
#pragma unroll
    for (int ni = 0; ni < 4; ni++) {
      const int col = colBase + wn * 64 + ni * 16 + fr;
      const float bb = bias[col];
#pragma unroll
      for (int mi = 0; mi < 8; mi++)
#pragma unroll
        for (int j = 0; j < 4; j++) {
          const size_t row = (size_t)rowBase + wm * 128 + mi * 16 + fg * 4 + j;
          C[row * (size_t)ldc + col] = f2bs(acc[mi][ni][j] + bb);
        }
    }
  } else if (EPI == 1) {
    short* C = (short*)Cp + (size_t)bz * Cbatch;
    bool mk[4];
    int cols[4];
#pragma unroll
    for (int ni = 0; ni < 4; ni++) {
      cols[ni] = colBase + wn * 64 + ni * 16 + fr;
      mk[ni] = cols[ni] < cntv;
    }
#pragma unroll
    for (int mi = 0; mi < 8; mi++)
#pragma unroll
      for (int j = 0; j < 4; j++) {
        const int rowl = rowBase + wm * 128 + mi * 16 + fg * 4 + j;
        float s = 0.f;
#pragma unroll
        for (int ni = 0; ni < 4; ni++) {
          const float e = mk[ni] ? __expf(fminf(acc[mi][ni][j] * scale, 30.f)) : 0.f;
          const short eb = f2bs(e);
          C[(size_t)rowl * (size_t)ldc + cols[ni]] = eb;
          s += b2f(eb);
        }
        s += __shfl_xor(s, 1, 64);
        s += __shfl_xor(s, 2, 64);
        s += __shfl_xor(s, 4, 64);
        s += __shfl_xor(s, 8, 64);
        if ((l & 15) == 0)
          partial[((size_t)bz * 1024 + rowl) * 32 + bx * 4 + wn] = s;
      }
  } else if (EPI == 3) {
    short* C = (short*)Cp + (size_t)bz * Cbatch;
#pragma unroll
    for (int mi = 0; mi < 8; mi++) {
      f32x4 b4 = *(const f32x4*)&bias[rowBase + wm * 128 + mi * 16 + fg * 4];
#pragma unroll
      for (int ni = 0; ni < 4; ni++) {
        const int col = colBase + wn * 64 + ni * 16 + fr;
#pragma unroll
        for (int j = 0; j < 4; j++) {
          const size_t row = (size_t)rowBase + wm * 128 + mi * 16 + fg * 4 + j;
          C[row * (size_t)ldc + col] = f2bs(acc[mi][ni][j] + b4[j]);
        }
      }
    }
  } else {
    // EPI 5: PV, multiply by rsinv[row], bf16 out
    short* C = (short*)Cp + (size_t)bz * Cbatch;
#pragma unroll
    for (int mi = 0; mi < 8; mi++) {
      const int rbase = rowBase + wm * 128 + mi * 16 + fg * 4;
      f32x4 rv = *(const f32x4*)&rsinv[(size_t)bz * 1024 + rbase];
#pragma unroll
      for (int ni = 0; ni < 4; ni++) {
        const int col = colBase + wn * 64 + ni * 16 + fr;
#pragma unroll
        for (int j = 0; j < 4; j++)
          C[((size_t)rbase + j) * (size_t)ldc + col] = f2bs(acc[mi][ni][j] * rv[j]);
      }
    }
  }
}

// ---- standalone GEMM, 3D grid with XCD swizzle ----------------------------
template <int EPI, int EXIT>
__global__ __launch_bounds__(512, 2) void gemm8_kernel(
    const short* __restrict__ A, const short* __restrict__ B, void* __restrict__ Cp,
    int K, int ldc, long Abatch, long Bbatch, long Cbatch,
    const float* __restrict__ bias, float scale,
    float* __restrict__ partial, const float* __restrict__ rsinv,
    const int* __restrict__ cnt) {
  __shared__ short lds[65536];
  const int gx = gridDim.x, gy = gridDim.y;
  const int nwg = gx * gy * (int)gridDim.z;
  int lin = blockIdx.x + gx * (blockIdx.y + gy * blockIdx.z);
  lin = (lin & 7) * (nwg >> 3) + (lin >> 3);
  const int bx = lin % gx;
  const int by = (lin / gx) % gy;
  const int bz = lin / (gx * gy);
  gemm_core<EPI, EXIT>(A, B, Cp, K, ldc, Abatch, Bbatch, Cbatch, bias, scale,
                       partial, rsinv, cnt, bx, by, bz, lds);
}

// ---------------- row-sum reduce: rsinv = 1 / sum(partial[row][0..20)) -----
__global__ __launch_bounds__(256) void rsum_kernel(const float* __restrict__ partial,
                                                   float* __restrict__ rsinv) {
  const size_t r = (size_t)blockIdx.x * 256 + threadIdx.x;
  float s = 0.f;
#pragma unroll
  for (int j = 0; j < 5; j++) {
    f32x4 a = *(const f32x4*)(partial + r * 32 + j * 4);
    s += (a[0] + a[1]) + (a[2] + a[3]);
  }
  rsinv[r] = 1.f / fmaxf(s, 1e-30f);
}

// -------- final LayerNorm: bf16 in (cross), fp32 out (d_out) ---------------
__global__ __launch_bounds__(256) void final_ln_kernel(const short* __restrict__ X,
                                                       const float* __restrict__ g,
                                                       const float* __restrict__ b,
                                                       float* __restrict__ Y) {
  const size_t row = (size_t)blockIdx.x * 4 + (threadIdx.x >> 6);
  const int lane = threadIdx.x & 63;
  const short* r = X + row * 1024;
  float f[16];
  float s = 0.f, ss = 0.f;
#pragma unroll
  for (int j = 0; j < 2; j++) {
    short8 v = *(const short8*)(r + j * 512 + lane * 8);
#pragma unroll
    for (int i = 0; i < 8; i++) {
      float x = b2f(v[i]);
      f[j * 8 + i] = x;
      s += x;
      ss += x * x;
    }
  }
  for (int o = 32; o > 0; o >>= 1) { s += __shfl_xor(s, o, 64); ss += __shfl_xor(ss, o, 64); }
  const float m = s * (1.f / 1024.f);
  const float rstd = rsqrtf(ss * (1.f / 1024.f) - m * m + 1e-5f);
#pragma unroll
  for (int j = 0; j < 2; j++) {
#pragma unroll
    for (int q = 0; q < 2; q++) {
      const int off = j * 512 + lane * 8 + q * 4;
      f32x4 gg = *(const f32x4*)(g + off);
      f32x4 bb = *(const f32x4*)(b + off);
      f32x4 y;
#pragma unroll
      for (int c = 0; c < 4; c++) y[c] = (f[j * 8 + q * 4 + c] - m) * rstd * gg[c] + bb[c];
      *(f32x4*)(Y + row * 1024 + off) = y;
    }
  }
}

extern "C" void kernel_launch(void* const* d_in, const int* in_sizes, int n_in,
                              void* d_out, int out_size, void* d_ws, size_t ws_size,
                              hipStream_t stream) {
  const float* text = (const float*)d_in[0];
  const float* audio = (const float*)d_in[1];
  const int* amask = (const int*)d_in[2];
  const float* ln_t_g = (const float*)d_in[3];
  const float* ln_t_b = (const float*)d_in[4];
  const float* ln_a_g = (const float*)d_in[5];
  const float* ln_a_b = (const float*)d_in[6];
  const float* Wq = (const float*)d_in[7];
  const float* bq = (const float*)d_in[8];
  const float* Wk = (const float*)d_in[9];
  const float* bk = (const float*)d_in[10];
  const float* Wv = (const float*)d_in[11];
  const float* bv = (const float*)d_in[12];
  const float* ln_p_g = (const float*)d_in[13];
  const float* ln_p_b = (const float*)d_in[14];

  char* p = (char*)d_ws;
  short* tb = (short*)p;  p += (size_t)32768 * 1024 * 2;      // 64 MB  (LN text)
  short* ab = (short*)p;  p += (size_t)65536 * 1024 * 2;      // 128 MB (LN audio, compacted)
  short* Wqt = (short*)p; p += (size_t)1024 * 1024 * 2;
  short* Wkt = (short*)p; p += (size_t)1024 * 1024 * 2;
  short* Wvt = (short*)p; p += (size_t)1024 * 1024 * 2;
  short* qb = (short*)p;  p += (size_t)32768 * 1024 * 2;      // 64 MB
  short* kb = (short*)p;  p += (size_t)65536 * 1024 * 2;      // 128 MB (compacted rows)
  short* vTb = (short*)p; p += (size_t)32 * 1024 * 2048 * 2;  // 128 MB [b][d][s-compact]
  float* partial = (float*)p; p += (size_t)32768 * 32 * 4;    // 4 MB
  float* rsinv = (float*)p;   p += (size_t)32768 * 4;         // 128 KB
  int* cpos = (int*)p;        p += (size_t)32 * 2048 * 4;     // 256 KB
  int* cnt = (int*)p;         p += 256;
  short* Pb = tb;       // P aliases tb+ab
  short* crossb = qb;   // cross aliases qb
  (void)ws_size; (void)in_sizes; (void)n_in; (void)out_size;

  // 0. mask prefix scan
  maskscan_kernel<<<32, 256, 0, stream>>>(amask, cpos, cnt);
  // 1. prep: LN (text + compacted audio) + weight transpose, one launch
  prep_kernel<<<24576 + 3072, 256, 0, stream>>>(
      text, audio, ln_t_g, ln_t_b, ln_a_g, ln_a_b, amask, cpos, tb, ab,
      Wq, Wk, Wv, Wqt, Wkt, Wvt);
  // 2. q = tb @ Wqt^T + bq   [32768 x 1024]
  gemm8_kernel<0, 0><<<dim3(4, 128, 1), 512, 0, stream>>>(
      tb, Wqt, qb, 1024, 1024, 0, 0, 0, bq, 0.f, nullptr, nullptr, nullptr);
  // 3. kc = ab_c @ Wkt^T + bk per batch; rows capped at 1280 (cnt<=1280 a.s.)
  gemm8_kernel<0, 1><<<dim3(4, 5, 32), 512, 0, stream>>>(
      ab, Wkt, kb, 1024, 1024, (long)2048 * 1024, 0, (long)2048 * 1024,
      bk, 0.f, nullptr, nullptr, cnt);
  // 4. vTc = (ab_c @ Wvt^T + bv)^T; cols capped at 1280
  gemm8_kernel<3, 2><<<dim3(5, 4, 32), 512, 0, stream>>>(
      Wvt, ab, vTb, 1024, 2048, 0, (long)2048 * 1024, (long)1024 * 2048,
      bv, 0.f, nullptr, nullptr, cnt);
  // 5. P = exp(scale * q@kc^T) for col<cnt -> bf16 + row partials; cols<=1280
  gemm8_kernel<1, 2><<<dim3(5, 4, 32), 512, 0, stream>>>(
      qb, kb, Pb, 1024, 2048, (long)1024 * 1024, (long)2048 * 1024,
      (long)1024 * 2048, nullptr, 0.03125f, partial, nullptr, cnt);
  // 6. rsinv[row] = 1 / sum_j partial[row][j], j<20
  rsum_kernel<<<128, 256, 0, stream>>>(partial, rsinv);
  // 7. cross = (P @ vTc^T) * rsinv -> bf16, dynamic K-trip = ceil(cnt/64)
  gemm8_kernel<5, 0><<<dim3(4, 4, 32), 512, 0, stream>>>(
      Pb, vTb, crossb, 2048, 1024, (long)1024 * 2048, (long)1024 * 2048,
      (long)1024 * 1024, nullptr, 0.f, nullptr, rsinv, cnt);
  // 8. final LayerNorm: crossb (bf16) -> d_out (fp32)
  final_ln_kernel<<<8192, 256, 0, stream>>>(crossb, ln_p_g, ln_p_b, (float*)d_out);
}